// Round 4
// baseline (1050.534 us; speedup 1.0000x reference)
//
#include <hip/hip_runtime.h>
#include <math.h>

#define TBn 16
#define Lpx 3136
#define CHW 301056      // 96*3136
#define SZn 4816896     // 16*96*3136
#define PRJ 1605632     // 16*32*3136
#define NPAD 3328       // 256*13

__device__ __forceinline__ float siluf_(float z){ return z / (1.f + expf(-z)); }
__device__ __forceinline__ float softplusf_(float z){ return fmaxf(z,0.f) + log1pf(expf(-fabsf(z))); }

// ---------------- per-pixel channel matmul: out[n,co,p] = sum_ci W[co,ci]*in[n,ci,p] (+bias) ----------------
__global__ __launch_bounds__(256) void k_matmul(const float* __restrict__ in, const float* __restrict__ Wm,
                                                const float* __restrict__ bias, float* __restrict__ out){
  int blk = blockIdx.x;
  int n = blk / 49, pt = blk % 49, p0 = pt * 64;
  __shared__ float lx[96*64];    // [ci][px]
  __shared__ float wl[96*33];    // [co][ci(32)+pad]
  int tid = threadIdx.x;
  const float* inb = in + (size_t)n*CHW;
  for (int i = tid; i < 96*64; i += 256){
    int ci = i >> 6, px = i & 63;
    lx[i] = inb[(size_t)ci*Lpx + p0 + px];
  }
  int px_t = tid & 15, co_t = tid >> 4;   // px base px_t*4, co base co_t*6
  float acc[6][4];
  #pragma unroll
  for (int j = 0; j < 6; ++j){
    float b = bias ? bias[co_t*6 + j] : 0.f;
    #pragma unroll
    for (int q = 0; q < 4; ++q) acc[j][q] = b;
  }
  for (int cc = 0; cc < 3; ++cc){
    __syncthreads();
    for (int i = tid; i < 96*32; i += 256){
      int co = i >> 5, ci = i & 31;
      wl[co*33 + ci] = Wm[co*96 + cc*32 + ci];
    }
    __syncthreads();
    for (int ci = 0; ci < 32; ++ci){
      float4 xv = *(const float4*)&lx[(cc*32 + ci)*64 + px_t*4];
      #pragma unroll
      for (int j = 0; j < 6; ++j){
        float w = wl[(co_t*6 + j)*33 + ci];
        acc[j][0] = fmaf(w, xv.x, acc[j][0]);
        acc[j][1] = fmaf(w, xv.y, acc[j][1]);
        acc[j][2] = fmaf(w, xv.z, acc[j][2]);
        acc[j][3] = fmaf(w, xv.w, acc[j][3]);
      }
    }
  }
  float* ob = out + (size_t)n*CHW + p0 + px_t*4;
  #pragma unroll
  for (int j = 0; j < 6; ++j){
    float4 v; v.x = acc[j][0]; v.y = acc[j][1]; v.z = acc[j][2]; v.w = acc[j][3];
    *(float4*)&ob[(size_t)(co_t*6 + j)*Lpx] = v;
  }
}

// ---------------- LIF over 16 steps, float4, uchar spike output ----------------
__global__ __launch_bounds__(256) void k_lif1(const float* __restrict__ xp, unsigned char* __restrict__ sp){
  int i4 = blockIdx.x*256 + threadIdx.x;     // < CHW/4
  float4 v = {0.f,0.f,0.f,0.f};
  #pragma unroll
  for (int t = 0; t < 16; ++t){
    float4 z = *(const float4*)&xp[(size_t)t*CHW + (size_t)i4*4];
    v.x = 0.5f*(v.x + z.x); v.y = 0.5f*(v.y + z.y);
    v.z = 0.5f*(v.z + z.z); v.w = 0.5f*(v.w + z.w);
    uchar4 s;
    s.x = (v.x >= 1.0f); s.y = (v.y >= 1.0f); s.z = (v.z >= 1.0f); s.w = (v.w >= 1.0f);
    *(uchar4*)&sp[(size_t)t*CHW + (size_t)i4*4] = s;
    v.x = s.x ? 0.f : v.x; v.y = s.y ? 0.f : v.y;
    v.z = s.z ? 0.f : v.z; v.w = s.w ? 0.f : v.w;
  }
}

// ---------------- dense 3x3 conv (96->96) + bias + silu, register-tiled ----------------
// thread: 4 px x 8 co; block: co-block 16, h-block 8, full w
#define CIC2 16
__global__ __launch_bounds__(256) void k_conv2(const unsigned char* __restrict__ spk, const float* __restrict__ cw,
                                               const float* __restrict__ cb, float* __restrict__ out){
  int b = blockIdx.x, cog = blockIdx.y, hb = blockIdx.z;
  int co0 = cog*16, h0 = hb*8;
  int tid = threadIdx.x;
  int wq = tid % 14, coh = (tid/14) % 2, hl = tid / 28;   // active if tid<224
  bool act = tid < 224;
  __shared__ float xl[CIC2*10*59];      // [ci][hh 0..9][ww 0..57, pad 59]
  __shared__ float wl[CIC2*9*16];       // [ci][tap][co]
  float acc[8][4];
  #pragma unroll
  for (int j = 0; j < 8; ++j)
    #pragma unroll
    for (int q = 0; q < 4; ++q) acc[j][q] = 0.f;

  for (int cc = 0; cc < 6; ++cc){
    __syncthreads();
    for (int i = tid; i < CIC2*10*58; i += 256){
      int ci = i / 580, rem = i % 580;
      int hh = rem / 58, ww = rem % 58;
      int sh = h0 - 1 + hh, sw = ww - 1;
      float v = 0.f;
      if (sh >= 0 && sh < 56 && sw >= 0 && sw < 56)
        v = (float)spk[(((size_t)b*96 + cc*CIC2 + ci)*56 + sh)*56 + sw];
      xl[ci*590 + hh*59 + ww] = v;
    }
    for (int i = tid; i < CIC2*9*16; i += 256){
      int ci = i / 144, rem = i % 144;
      int tap = rem / 16, co = rem % 16;
      wl[i] = cw[(((size_t)(co0+co))*96 + cc*CIC2 + ci)*9 + tap];
    }
    __syncthreads();
    if (act){
      for (int ci = 0; ci < CIC2; ++ci){
        float xr[3][6];
        int base = ci*590 + hl*59 + wq*4;
        #pragma unroll
        for (int dh = 0; dh < 3; ++dh)
          #pragma unroll
          for (int t = 0; t < 6; ++t) xr[dh][t] = xl[base + dh*59 + t];
        #pragma unroll
        for (int tap = 0; tap < 9; ++tap){
          int dh = tap/3, dw = tap%3;
          const float4* wp = (const float4*)&wl[(ci*9 + tap)*16 + coh*8];
          float4 w0 = wp[0], w1 = wp[1];
          #pragma unroll
          for (int q = 0; q < 4; ++q){
            float xv = xr[dh][q + dw];
            acc[0][q] = fmaf(xv, w0.x, acc[0][q]);
            acc[1][q] = fmaf(xv, w0.y, acc[1][q]);
            acc[2][q] = fmaf(xv, w0.z, acc[2][q]);
            acc[3][q] = fmaf(xv, w0.w, acc[3][q]);
            acc[4][q] = fmaf(xv, w1.x, acc[4][q]);
            acc[5][q] = fmaf(xv, w1.y, acc[5][q]);
            acc[6][q] = fmaf(xv, w1.z, acc[6][q]);
            acc[7][q] = fmaf(xv, w1.w, acc[7][q]);
          }
        }
      }
    }
  }
  if (act){
    #pragma unroll
    for (int j = 0; j < 8; ++j){
      int co = co0 + coh*8 + j;
      float bv = cb[co];
      float4 o;
      o.x = siluf_(acc[j][0] + bv); o.y = siluf_(acc[j][1] + bv);
      o.z = siluf_(acc[j][2] + bv); o.w = siluf_(acc[j][3] + bv);
      *(float4*)&out[(((size_t)b*96 + co)*56 + h0 + hl)*56 + wq*4] = o;
    }
  }
}

// ---------------- depthwise 3x3 + silu, writes row-major and transposed ----------------
__global__ __launch_bounds__(256) void k_dwconv(const float* __restrict__ xin, const float* __restrict__ dwW,
                                                float* __restrict__ out, float* __restrict__ outT){
  int bd = blockIdx.x;           // b*96+d
  int d = bd % 96;
  const float* ip = xin + (size_t)bd*Lpx;
  __shared__ float pl[Lpx];
  __shared__ float po[Lpx + 56];
  int tid = threadIdx.x;
  for (int i = tid; i < Lpx; i += 256) pl[i] = ip[i];
  float w9[9];
  #pragma unroll
  for (int t = 0; t < 9; ++t) w9[t] = dwW[d*9 + t];
  __syncthreads();
  for (int i = tid; i < Lpx; i += 256){
    int h = i / 56, w = i % 56;
    float s = 0.f;
    #pragma unroll
    for (int tap = 0; tap < 9; ++tap){
      int hh = h + tap/3 - 1, ww = w + tap%3 - 1;
      if (hh >= 0 && hh < 56 && ww >= 0 && ww < 56) s = fmaf(pl[hh*56 + ww], w9[tap], s);
    }
    po[i + i/56] = siluf_(s);
  }
  __syncthreads();
  float* op  = out  + (size_t)bd*Lpx;
  float* otp = outT + (size_t)bd*Lpx;
  for (int i = tid; i < Lpx; i += 256){
    op[i] = po[i + i/56];
    int q = (i % 56)*56 + i/56;
    otp[i] = po[q + q/56];        // stride-57 LDS read: conflict-free
  }
}

// ---------------- per-pixel 96->(4k x 8r) projections, row-major and transposed ----------------
__global__ __launch_bounds__(256) void k_proj(const float* __restrict__ xss, const float* __restrict__ xpw,
                                              float* __restrict__ PROJ, float* __restrict__ PROJT){
  int b = blockIdx.x / 56, h = blockIdx.x % 56;
  __shared__ float lx[96*56];    // [d][w]
  __shared__ float lw[32*96];    // [kr][d]
  int tid = threadIdx.x;
  const float* xb = xss + (size_t)b*CHW + h*56;
  for (int i = tid; i < 96*56; i += 256){
    int d = i / 56, w = i % 56;
    lx[i] = xb[(size_t)d*Lpx + w];
  }
  for (int i = tid; i < 32*96; i += 256) lw[i] = xpw[i];
  __syncthreads();
  for (int o = tid; o < 32*56; o += 256){
    int w = o % 56, kr = o / 56;
    float s = 0.f;
    for (int d = 0; d < 96; ++d) s = fmaf(lx[d*56 + w], lw[kr*96 + d], s);
    size_t base = ((size_t)b*32 + kr)*Lpx;
    PROJ[base + h*56 + w] = s;
    PROJT[base + w*56 + h] = s;
  }
}

// ---------------- block-parallel bidirectional selective scan ----------------
__global__ __launch_bounds__(256) void k_scan2(const float* __restrict__ x_rm, const float* __restrict__ x_cm,
                                               const float* __restrict__ PROJ, const float* __restrict__ PROJT,
                                               const float* __restrict__ dtw_all, const float* __restrict__ dtb_all,
                                               const float* __restrict__ Alog, const float* __restrict__ Dall,
                                               float* __restrict__ out0, float* __restrict__ out1){
  int bd = blockIdx.x; int b = bd / 96, d = bd % 96;
  int klo = blockIdx.y;
  const float* xv = (klo == 0 ? x_rm : x_cm) + (size_t)bd*Lpx;
  const float* PR = (klo == 0 ? PROJ : PROJT);
  float* yo = (klo == 0 ? out0 : out1) + (size_t)bd*Lpx;
  int kA = klo, kB = klo + 2;

  float dwA[6], dwB[6];
  #pragma unroll
  for (int r = 0; r < 6; ++r){ dwA[r] = dtw_all[(kA*96 + d)*6 + r]; dwB[r] = dtw_all[(kB*96 + d)*6 + r]; }
  float biA = dtb_all[kA*96 + d], biB = dtb_all[kB*96 + d];
  float AA = -expf(Alog[kA*96 + d]), AB = -expf(Alog[kB*96 + d]);
  float Dsum = Dall[kA*96 + d] + Dall[kB*96 + d];
  const float* pA = PR + ((size_t)b*32 + kA*8)*Lpx;
  const float* pB = PR + ((size_t)b*32 + kB*8)*Lpx;

  __shared__ float xb[Lpx];
  __shared__ float u[NPAD];
  __shared__ float v[NPAD];
  __shared__ float yacc[Lpx + 56];
  __shared__ float wag[8];

  int tid = threadIdx.x;
  int lane = tid & 63, wv = tid >> 6;
  int base = tid * 13;

  for (int i = tid; i < Lpx; i += 256) xb[i] = xv[i];

  // ======== direction A (forward in p) ========
  for (int i = tid; i < Lpx; i += 256){
    float z = biA;
    #pragma unroll
    for (int r = 0; r < 6; ++r) z = fmaf(dwA[r], pA[(size_t)r*Lpx + i], z);
    float dt = softplusf_(z);
    u[i] = expf(dt * AA);
    v[i] = dt * pA[(size_t)6*Lpx + i] * xb[i];
  }
  for (int i = Lpx + tid; i < NPAD; i += 256){ u[i] = 1.f; v[i] = 0.f; }
  __syncthreads();

  {
    float a = 1.f, bb = 0.f;
    #pragma unroll
    for (int j = 0; j < 13; ++j){
      float da = u[base + j], db = v[base + j];
      bb = fmaf(da, bb, db);
      a *= da;
      u[base + j] = a; v[base + j] = bb;
    }
    float aT = a, bT = bb;
    #pragma unroll
    for (int off = 1; off < 64; off <<= 1){
      float ap = __shfl_up(aT, off), bp = __shfl_up(bT, off);
      if (lane >= off){ bT = fmaf(aT, bp, bT); aT *= ap; }
    }
    if (lane == 63){ wag[wv] = aT; wag[4 + wv] = bT; }
    float a_ex = __shfl_up(aT, 1), b_ex = __shfl_up(bT, 1);
    if (lane == 0){ a_ex = 1.f; b_ex = 0.f; }
    __syncthreads();
    float hw = 0.f;
    for (int j = 0; j < wv; ++j) hw = fmaf(wag[j], hw, wag[4 + j]);
    float hin = fmaf(a_ex, hw, b_ex);
    #pragma unroll
    for (int j = 0; j < 13; ++j)
      v[base + j] = fmaf(u[base + j], hin, v[base + j]);
  }
  __syncthreads();
  for (int i = tid; i < Lpx; i += 256){
    float C = pA[(size_t)7*Lpx + i];
    yacc[i + i/56] = fmaf(C, v[i], Dsum * xb[i]);
  }
  __syncthreads();

  // ======== direction B (reverse in p) ========
  for (int i = tid; i < Lpx; i += 256){
    float z = biB;
    #pragma unroll
    for (int r = 0; r < 6; ++r) z = fmaf(dwB[r], pB[(size_t)r*Lpx + i], z);
    float dt = softplusf_(z);
    u[i] = expf(dt * AB);
    v[i] = dt * pB[(size_t)6*Lpx + i] * xb[i];
  }
  for (int i = Lpx + tid; i < NPAD; i += 256){ u[i] = 1.f; v[i] = 0.f; }
  __syncthreads();

  {
    float a = 1.f, bb = 0.f;
    #pragma unroll
    for (int j = 12; j >= 0; --j){
      float da = u[base + j], db = v[base + j];
      bb = fmaf(da, bb, db);
      a *= da;
      u[base + j] = a; v[base + j] = bb;
    }
    float aT = a, bT = bb;
    #pragma unroll
    for (int off = 1; off < 64; off <<= 1){
      float ap = __shfl_down(aT, off), bp = __shfl_down(bT, off);
      if (lane + off < 64){ bT = fmaf(aT, bp, bT); aT *= ap; }
    }
    if (lane == 0){ wag[wv] = aT; wag[4 + wv] = bT; }
    float a_ex = __shfl_down(aT, 1), b_ex = __shfl_down(bT, 1);
    if (lane == 63){ a_ex = 1.f; b_ex = 0.f; }
    __syncthreads();
    float hw = 0.f;
    for (int j = 3; j > wv; --j) hw = fmaf(wag[j], hw, wag[4 + j]);
    float hin = fmaf(a_ex, hw, b_ex);
    #pragma unroll
    for (int j = 0; j < 13; ++j)
      v[base + j] = fmaf(u[base + j], hin, v[base + j]);
  }
  __syncthreads();
  for (int i = tid; i < Lpx; i += 256){
    float C = pB[(size_t)7*Lpx + i];
    yacc[i + i/56] = fmaf(C, v[i], yacc[i + i/56]);
  }
  __syncthreads();

  if (klo == 0){
    for (int i = tid; i < Lpx; i += 256)
      yo[i] = yacc[i + i/56];
  } else {
    for (int i = tid; i < Lpx; i += 256){
      int q = (i % 56)*56 + i/56;
      yo[i] = yacc[q + q/56];
    }
  }
}

// ---------------- combine ya+yb, LayerNorm over channels (float4) ----------------
__global__ __launch_bounds__(256) void k_ln(const float* __restrict__ ya, const float* __restrict__ yb,
                                            const float* __restrict__ g, const float* __restrict__ be,
                                            float* __restrict__ out){
  int i4 = blockIdx.x*256 + threadIdx.x;    // < 16*784
  int b = i4 / 784, p = (i4 % 784) * 4;
  const float* ap = ya + (size_t)b*CHW + p;
  const float* bp = yb + (size_t)b*CHW + p;
  float4 s = {0.f,0.f,0.f,0.f};
  for (int d = 0; d < 96; ++d){
    float4 av = *(const float4*)&ap[(size_t)d*Lpx];
    float4 bv = *(const float4*)&bp[(size_t)d*Lpx];
    s.x += av.x + bv.x; s.y += av.y + bv.y; s.z += av.z + bv.z; s.w += av.w + bv.w;
  }
  float4 mu; mu.x = s.x*(1.f/96.f); mu.y = s.y*(1.f/96.f); mu.z = s.z*(1.f/96.f); mu.w = s.w*(1.f/96.f);
  float4 ss = {0.f,0.f,0.f,0.f};
  for (int d = 0; d < 96; ++d){
    float4 av = *(const float4*)&ap[(size_t)d*Lpx];
    float4 bv = *(const float4*)&bp[(size_t)d*Lpx];
    float vx = av.x + bv.x - mu.x, vy = av.y + bv.y - mu.y;
    float vz = av.z + bv.z - mu.z, vw = av.w + bv.w - mu.w;
    ss.x = fmaf(vx,vx,ss.x); ss.y = fmaf(vy,vy,ss.y); ss.z = fmaf(vz,vz,ss.z); ss.w = fmaf(vw,vw,ss.w);
  }
  float4 rs;
  rs.x = 1.f/sqrtf(ss.x*(1.f/96.f) + 1e-5f); rs.y = 1.f/sqrtf(ss.y*(1.f/96.f) + 1e-5f);
  rs.z = 1.f/sqrtf(ss.z*(1.f/96.f) + 1e-5f); rs.w = 1.f/sqrtf(ss.w*(1.f/96.f) + 1e-5f);
  float* op = out + (size_t)b*CHW + p;
  for (int d = 0; d < 96; ++d){
    float4 av = *(const float4*)&ap[(size_t)d*Lpx];
    float4 bv = *(const float4*)&bp[(size_t)d*Lpx];
    float gd = g[d], bd = be[d];
    float4 o;
    o.x = (av.x + bv.x - mu.x)*rs.x*gd + bd;
    o.y = (av.y + bv.y - mu.y)*rs.y*gd + bd;
    o.z = (av.z + bv.z - mu.z)*rs.z*gd + bd;
    o.w = (av.w + bv.w - mu.w)*rs.w*gd + bd;
    *(float4*)&op[(size_t)d*Lpx] = o;
  }
}

// ---------------- LIF over T=4 + multiply with original x (float4) ----------------
__global__ __launch_bounds__(256) void k_lif2(const float* __restrict__ yo, const float* __restrict__ x0,
                                              float* __restrict__ out){
  const int stride4 = 301056;   // B*C*L/4
  int i4 = blockIdx.x*256 + threadIdx.x;
  float4 v = {0.f,0.f,0.f,0.f};
  #pragma unroll
  for (int t = 0; t < 4; ++t){
    float4 z = *(const float4*)&yo[((size_t)t*stride4 + i4)*4];
    float4 xv = *(const float4*)&x0[((size_t)t*stride4 + i4)*4];
    v.x = 0.5f*(v.x + z.x); v.y = 0.5f*(v.y + z.y);
    v.z = 0.5f*(v.z + z.z); v.w = 0.5f*(v.w + z.w);
    float4 o;
    o.x = (v.x >= 1.0f) ? xv.x : 0.f; o.y = (v.y >= 1.0f) ? xv.y : 0.f;
    o.z = (v.z >= 1.0f) ? xv.z : 0.f; o.w = (v.w >= 1.0f) ? xv.w : 0.f;
    v.x = (v.x >= 1.0f) ? 0.f : v.x; v.y = (v.y >= 1.0f) ? 0.f : v.y;
    v.z = (v.z >= 1.0f) ? 0.f : v.z; v.w = (v.w >= 1.0f) ? 0.f : v.w;
    *(float4*)&out[((size_t)t*stride4 + i4)*4] = o;
  }
}

extern "C" void kernel_launch(void* const* d_in, const int* in_sizes, int n_in,
                              void* d_out, int out_size, void* d_ws, size_t ws_size,
                              hipStream_t stream) {
  const float* x    = (const float*)d_in[0];
  const float* ipw  = (const float*)d_in[1];
  const float* ipb  = (const float*)d_in[2];
  const float* cw   = (const float*)d_in[3];
  const float* cb   = (const float*)d_in[4];
  const float* siw  = (const float*)d_in[5];
  const float* scw  = (const float*)d_in[6];
  const float* xpw  = (const float*)d_in[7];
  const float* dtw  = (const float*)d_in[8];
  const float* dtb  = (const float*)d_in[9];
  const float* alog = (const float*)d_in[10];
  const float* dsv  = (const float*)d_in[11];
  const float* lng  = (const float*)d_in[12];
  const float* lnb  = (const float*)d_in[13];
  const float* opw  = (const float*)d_in[14];

  float* s1 = (float*)d_ws;
  float* s2 = s1 + SZn;
  float* s3 = s2 + SZn;
  float* s4 = s3 + SZn;
  float* pr  = s4 + SZn;
  float* prT = pr + PRJ;

  // 1) in_proj -> xp in s1
  k_matmul<<<784, 256, 0, stream>>>(x, ipw, ipb, s1);
  // 2) LIF over 16 steps -> uchar spikes in s2
  k_lif1<<<294, 256, 0, stream>>>(s1, (unsigned char*)s2);
  // 3) dense 3x3 conv + bias + silu -> xc in s1
  k_conv2<<<dim3(16, 6, 7), 256, 0, stream>>>((const unsigned char*)s2, cw, cb, s1);
  // 4) ssm_in matmul -> s2
  k_matmul<<<784, 256, 0, stream>>>(s1, siw, nullptr, s2);
  // 5) depthwise conv + silu -> xss rm in s1, cm in s3
  k_dwconv<<<1536, 256, 0, stream>>>(s2, scw, s1, s3);
  // 6) projections (pixel-indexed, both layouts)
  k_proj<<<896, 256, 0, stream>>>(s1, xpw, pr, prT);
  // 7) both scan dir-pairs: ya -> s2, yb(row-major) -> s4
  k_scan2<<<dim3(1536, 2), 256, 0, stream>>>(s1, s3, pr, prT, dtw, dtb, alog, dsv, s2, s4);
  // 8) combine + LayerNorm -> s3
  k_ln<<<49, 256, 0, stream>>>(s2, s4, lng, lnb, s3);
  // 9) out_proj -> s2
  k_matmul<<<784, 256, 0, stream>>>(s3, opw, nullptr, s2);
  // 10) LIF over T=4, multiply with x -> d_out
  k_lif2<<<1176, 256, 0, stream>>>(s2, x, (float*)d_out);
}

// Round 8
// 991.094 us; speedup vs baseline: 1.0600x; 1.0600x over previous
//
#include <hip/hip_runtime.h>
#include <math.h>

#define TBn 16
#define Lpx 3136
#define CHW 301056      // 96*3136
#define SZn 4816896     // 16*96*3136
#define PRJ 1605632     // 16*32*3136
#define NPAD 3328       // 256*13

__device__ __forceinline__ float siluf_(float z){ return z / (1.f + expf(-z)); }
__device__ __forceinline__ float softplusf_(float z){ return fmaxf(z,0.f) + log1pf(expf(-fabsf(z))); }

// ---------------- per-pixel channel matmul: out[n,co,p] = sum_ci W[co,ci]*in[n,ci,p] (+bias) ----------------
__global__ __launch_bounds__(256) void k_matmul(const float* __restrict__ in, const float* __restrict__ Wm,
                                                const float* __restrict__ bias, float* __restrict__ out){
  int blk = blockIdx.x;
  int n = blk / 49, pt = blk % 49, p0 = pt * 64;
  __shared__ float lx[96*64];    // [ci][px]
  __shared__ float wl[96*33];    // [co][ci(32)+pad]
  int tid = threadIdx.x;
  const float* inb = in + (size_t)n*CHW;
  for (int i = tid; i < 96*64; i += 256){
    int ci = i >> 6, px = i & 63;
    lx[i] = inb[(size_t)ci*Lpx + p0 + px];
  }
  int px_t = tid & 15, co_t = tid >> 4;   // px base px_t*4, co base co_t*6
  float acc[6][4];
  #pragma unroll
  for (int j = 0; j < 6; ++j){
    float b = bias ? bias[co_t*6 + j] : 0.f;
    #pragma unroll
    for (int q = 0; q < 4; ++q) acc[j][q] = b;
  }
  for (int cc = 0; cc < 3; ++cc){
    __syncthreads();
    for (int i = tid; i < 96*32; i += 256){
      int co = i >> 5, ci = i & 31;
      wl[co*33 + ci] = Wm[co*96 + cc*32 + ci];
    }
    __syncthreads();
    for (int ci = 0; ci < 32; ++ci){
      float4 xv = *(const float4*)&lx[(cc*32 + ci)*64 + px_t*4];
      #pragma unroll
      for (int j = 0; j < 6; ++j){
        float w = wl[(co_t*6 + j)*33 + ci];
        acc[j][0] = fmaf(w, xv.x, acc[j][0]);
        acc[j][1] = fmaf(w, xv.y, acc[j][1]);
        acc[j][2] = fmaf(w, xv.z, acc[j][2]);
        acc[j][3] = fmaf(w, xv.w, acc[j][3]);
      }
    }
  }
  float* ob = out + (size_t)n*CHW + p0 + px_t*4;
  #pragma unroll
  for (int j = 0; j < 6; ++j){
    float4 v; v.x = acc[j][0]; v.y = acc[j][1]; v.z = acc[j][2]; v.w = acc[j][3];
    *(float4*)&ob[(size_t)(co_t*6 + j)*Lpx] = v;
  }
}

// ---------------- LIF over 16 steps, float4, uchar spike output ----------------
__global__ __launch_bounds__(256) void k_lif1(const float* __restrict__ xp, unsigned char* __restrict__ sp){
  int i4 = blockIdx.x*256 + threadIdx.x;     // < CHW/4
  float4 v = {0.f,0.f,0.f,0.f};
  #pragma unroll
  for (int t = 0; t < 16; ++t){
    float4 z = *(const float4*)&xp[(size_t)t*CHW + (size_t)i4*4];
    v.x = 0.5f*(v.x + z.x); v.y = 0.5f*(v.y + z.y);
    v.z = 0.5f*(v.z + z.z); v.w = 0.5f*(v.w + z.w);
    uchar4 s;
    s.x = (v.x >= 1.0f); s.y = (v.y >= 1.0f); s.z = (v.z >= 1.0f); s.w = (v.w >= 1.0f);
    *(uchar4*)&sp[(size_t)t*CHW + (size_t)i4*4] = s;
    v.x = s.x ? 0.f : v.x; v.y = s.y ? 0.f : v.y;
    v.z = s.z ? 0.f : v.z; v.w = s.w ? 0.f : v.w;
  }
}

// ---------------- dense 3x3 conv (96->96) + bias + silu, v3 ----------------
// thread tile: 4 co x 1 h x 4 w; weights register-staged per (ci,tap) via one b128.
// block: 16 co x 4 h x 56 w; grid (16, 6, 14) = 1344 blocks; CIC=8 -> 16 KB LDS.
#define CIC3 8
__global__ __launch_bounds__(256) void k_conv3(const unsigned char* __restrict__ spk, const float* __restrict__ cw,
                                               const float* __restrict__ cb, float* __restrict__ out){
  int b = blockIdx.x, cog = blockIdx.y, hb = blockIdx.z;
  int co0 = cog*16, h0 = hb*4;
  int tid = threadIdx.x;
  int hl = tid / 56, rem2 = tid % 56;
  int coh = rem2 / 14, wq = rem2 % 14;       // active if tid < 224
  bool act = tid < 224;
  __shared__ float xl[CIC3*6*60];            // [ci][row 0..5][col 0..57, stride 60]
  __shared__ float wl[CIC3*9*16];            // [ci][tap][co]
  float acc[4][4];
  #pragma unroll
  for (int j = 0; j < 4; ++j)
    #pragma unroll
    for (int q = 0; q < 4; ++q) acc[j][q] = 0.f;

  for (int cc = 0; cc < 12; ++cc){
    __syncthreads();
    for (int i = tid; i < CIC3*6*58; i += 256){
      int ci = i / 348, rem = i % 348;
      int hh = rem / 58, ww = rem % 58;
      int sh = h0 - 1 + hh, sw = ww - 1;
      float v = 0.f;
      if (sh >= 0 && sh < 56 && sw >= 0 && sw < 56)
        v = (float)spk[(((size_t)b*96 + cc*CIC3 + ci)*56 + sh)*56 + sw];
      xl[ci*360 + hh*60 + ww] = v;
    }
    for (int i = tid; i < CIC3*9*16; i += 256){
      int ci = i / 144, rem = i % 144;
      int tap = rem / 16, co = rem % 16;
      wl[i] = cw[(((size_t)(co0+co))*96 + cc*CIC3 + ci)*9 + tap];
    }
    __syncthreads();
    if (act){
      for (int ci = 0; ci < CIC3; ++ci){
        float xr[3][6];
        int base = ci*360 + hl*60 + wq*4;
        #pragma unroll
        for (int dh = 0; dh < 3; ++dh)
          #pragma unroll
          for (int t = 0; t < 6; ++t) xr[dh][t] = xl[base + dh*60 + t];
        #pragma unroll
        for (int tap = 0; tap < 9; ++tap){
          int dh = tap/3, dw = tap%3;
          float4 w = *(const float4*)&wl[(ci*9 + tap)*16 + coh*4];
          #pragma unroll
          for (int q = 0; q < 4; ++q){
            float xv = xr[dh][q + dw];
            acc[0][q] = fmaf(xv, w.x, acc[0][q]);
            acc[1][q] = fmaf(xv, w.y, acc[1][q]);
            acc[2][q] = fmaf(xv, w.z, acc[2][q]);
            acc[3][q] = fmaf(xv, w.w, acc[3][q]);
          }
        }
      }
    }
  }
  if (act){
    #pragma unroll
    for (int j = 0; j < 4; ++j){
      int co = co0 + coh*4 + j;
      float bv = cb[co];
      float4 o;
      o.x = siluf_(acc[j][0] + bv); o.y = siluf_(acc[j][1] + bv);
      o.z = siluf_(acc[j][2] + bv); o.w = siluf_(acc[j][3] + bv);
      *(float4*)&out[(((size_t)b*96 + co)*56 + h0 + hl)*56 + wq*4] = o;
    }
  }
}

// ---------------- depthwise 3x3 + silu, writes row-major and transposed ----------------
__global__ __launch_bounds__(256) void k_dwconv(const float* __restrict__ xin, const float* __restrict__ dwW,
                                                float* __restrict__ out, float* __restrict__ outT){
  int bd = blockIdx.x;           // b*96+d
  int d = bd % 96;
  const float* ip = xin + (size_t)bd*Lpx;
  __shared__ float pl[Lpx];
  __shared__ float po[Lpx + 56];
  int tid = threadIdx.x;
  for (int i = tid; i < Lpx; i += 256) pl[i] = ip[i];
  float w9[9];
  #pragma unroll
  for (int t = 0; t < 9; ++t) w9[t] = dwW[d*9 + t];
  __syncthreads();
  for (int i = tid; i < Lpx; i += 256){
    int h = i / 56, w = i % 56;
    float s = 0.f;
    #pragma unroll
    for (int tap = 0; tap < 9; ++tap){
      int hh = h + tap/3 - 1, ww = w + tap%3 - 1;
      if (hh >= 0 && hh < 56 && ww >= 0 && ww < 56) s = fmaf(pl[hh*56 + ww], w9[tap], s);
    }
    po[i + i/56] = siluf_(s);
  }
  __syncthreads();
  float* op  = out  + (size_t)bd*Lpx;
  float* otp = outT + (size_t)bd*Lpx;
  for (int i = tid; i < Lpx; i += 256){
    op[i] = po[i + i/56];
    int q = (i % 56)*56 + i/56;
    otp[i] = po[q + q/56];        // stride-57 LDS read: conflict-free
  }
}

// ---------------- per-pixel 96->(4k x 8r) projections, row-major and transposed ----------------
__global__ __launch_bounds__(256) void k_proj(const float* __restrict__ xss, const float* __restrict__ xpw,
                                              float* __restrict__ PROJ, float* __restrict__ PROJT){
  int b = blockIdx.x / 56, h = blockIdx.x % 56;
  __shared__ float lx[96*56];    // [d][w]
  __shared__ float lw[32*96];    // [kr][d]
  int tid = threadIdx.x;
  const float* xb = xss + (size_t)b*CHW + h*56;
  for (int i = tid; i < 96*56; i += 256){
    int d = i / 56, w = i % 56;
    lx[i] = xb[(size_t)d*Lpx + w];
  }
  for (int i = tid; i < 32*96; i += 256) lw[i] = xpw[i];
  __syncthreads();
  for (int o = tid; o < 32*56; o += 256){
    int w = o % 56, kr = o / 56;
    float s = 0.f;
    for (int d = 0; d < 96; ++d) s = fmaf(lx[d*56 + w], lw[kr*96 + d], s);
    size_t base = ((size_t)b*32 + kr)*Lpx;
    PROJ[base + h*56 + w] = s;
    PROJT[base + w*56 + h] = s;
  }
}

// ---------------- block-parallel bidirectional selective scan ----------------
__global__ __launch_bounds__(256) void k_scan2(const float* __restrict__ x_rm, const float* __restrict__ x_cm,
                                               const float* __restrict__ PROJ, const float* __restrict__ PROJT,
                                               const float* __restrict__ dtw_all, const float* __restrict__ dtb_all,
                                               const float* __restrict__ Alog, const float* __restrict__ Dall,
                                               float* __restrict__ out0, float* __restrict__ out1){
  int bd = blockIdx.x; int b = bd / 96, d = bd % 96;
  int klo = blockIdx.y;
  const float* xv = (klo == 0 ? x_rm : x_cm) + (size_t)bd*Lpx;
  const float* PR = (klo == 0 ? PROJ : PROJT);
  float* yo = (klo == 0 ? out0 : out1) + (size_t)bd*Lpx;
  int kA = klo, kB = klo + 2;

  float dwA[6], dwB[6];
  #pragma unroll
  for (int r = 0; r < 6; ++r){ dwA[r] = dtw_all[(kA*96 + d)*6 + r]; dwB[r] = dtw_all[(kB*96 + d)*6 + r]; }
  float biA = dtb_all[kA*96 + d], biB = dtb_all[kB*96 + d];
  float AA = -expf(Alog[kA*96 + d]), AB = -expf(Alog[kB*96 + d]);
  float Dsum = Dall[kA*96 + d] + Dall[kB*96 + d];
  const float* pA = PR + ((size_t)b*32 + kA*8)*Lpx;
  const float* pB = PR + ((size_t)b*32 + kB*8)*Lpx;

  __shared__ float xb[Lpx];
  __shared__ float u[NPAD];
  __shared__ float v[NPAD];
  __shared__ float yacc[Lpx + 56];
  __shared__ float wag[8];

  int tid = threadIdx.x;
  int lane = tid & 63, wv = tid >> 6;
  int base = tid * 13;

  for (int i = tid; i < Lpx; i += 256) xb[i] = xv[i];

  // ======== direction A (forward in p) ========
  for (int i = tid; i < Lpx; i += 256){
    float z = biA;
    #pragma unroll
    for (int r = 0; r < 6; ++r) z = fmaf(dwA[r], pA[(size_t)r*Lpx + i], z);
    float dt = softplusf_(z);
    u[i] = expf(dt * AA);
    v[i] = dt * pA[(size_t)6*Lpx + i] * xb[i];
  }
  for (int i = Lpx + tid; i < NPAD; i += 256){ u[i] = 1.f; v[i] = 0.f; }
  __syncthreads();

  {
    float a = 1.f, bb = 0.f;
    #pragma unroll
    for (int j = 0; j < 13; ++j){
      float da = u[base + j], db = v[base + j];
      bb = fmaf(da, bb, db);
      a *= da;
      u[base + j] = a; v[base + j] = bb;
    }
    float aT = a, bT = bb;
    #pragma unroll
    for (int off = 1; off < 64; off <<= 1){
      float ap = __shfl_up(aT, off), bp = __shfl_up(bT, off);
      if (lane >= off){ bT = fmaf(aT, bp, bT); aT *= ap; }
    }
    if (lane == 63){ wag[wv] = aT; wag[4 + wv] = bT; }
    float a_ex = __shfl_up(aT, 1), b_ex = __shfl_up(bT, 1);
    if (lane == 0){ a_ex = 1.f; b_ex = 0.f; }
    __syncthreads();
    float hw = 0.f;
    for (int j = 0; j < wv; ++j) hw = fmaf(wag[j], hw, wag[4 + j]);
    float hin = fmaf(a_ex, hw, b_ex);
    #pragma unroll
    for (int j = 0; j < 13; ++j)
      v[base + j] = fmaf(u[base + j], hin, v[base + j]);
  }
  __syncthreads();
  for (int i = tid; i < Lpx; i += 256){
    float C = pA[(size_t)7*Lpx + i];
    yacc[i + i/56] = fmaf(C, v[i], Dsum * xb[i]);
  }
  __syncthreads();

  // ======== direction B (reverse in p) ========
  for (int i = tid; i < Lpx; i += 256){
    float z = biB;
    #pragma unroll
    for (int r = 0; r < 6; ++r) z = fmaf(dwB[r], pB[(size_t)r*Lpx + i], z);
    float dt = softplusf_(z);
    u[i] = expf(dt * AB);
    v[i] = dt * pB[(size_t)6*Lpx + i] * xb[i];
  }
  for (int i = Lpx + tid; i < NPAD; i += 256){ u[i] = 1.f; v[i] = 0.f; }
  __syncthreads();

  {
    float a = 1.f, bb = 0.f;
    #pragma unroll
    for (int j = 12; j >= 0; --j){
      float da = u[base + j], db = v[base + j];
      bb = fmaf(da, bb, db);
      a *= da;
      u[base + j] = a; v[base + j] = bb;
    }
    float aT = a, bT = bb;
    #pragma unroll
    for (int off = 1; off < 64; off <<= 1){
      float ap = __shfl_down(aT, off), bp = __shfl_down(bT, off);
      if (lane + off < 64){ bT = fmaf(aT, bp, bT); aT *= ap; }
    }
    if (lane == 0){ wag[wv] = aT; wag[4 + wv] = bT; }
    float a_ex = __shfl_down(aT, 1), b_ex = __shfl_down(bT, 1);
    if (lane == 63){ a_ex = 1.f; b_ex = 0.f; }
    __syncthreads();
    float hw = 0.f;
    for (int j = 3; j > wv; --j) hw = fmaf(wag[j], hw, wag[4 + j]);
    float hin = fmaf(a_ex, hw, b_ex);
    #pragma unroll
    for (int j = 0; j < 13; ++j)
      v[base + j] = fmaf(u[base + j], hin, v[base + j]);
  }
  __syncthreads();
  for (int i = tid; i < Lpx; i += 256){
    float C = pB[(size_t)7*Lpx + i];
    yacc[i + i/56] = fmaf(C, v[i], yacc[i + i/56]);
  }
  __syncthreads();

  if (klo == 0){
    for (int i = tid; i < Lpx; i += 256)
      yo[i] = yacc[i + i/56];
  } else {
    for (int i = tid; i < Lpx; i += 256){
      int q = (i % 56)*56 + i/56;
      yo[i] = yacc[q + q/56];
    }
  }
}

// ---------------- combine ya+yb, LayerNorm over channels (float4) ----------------
__global__ __launch_bounds__(256) void k_ln(const float* __restrict__ ya, const float* __restrict__ yb,
                                            const float* __restrict__ g, const float* __restrict__ be,
                                            float* __restrict__ out){
  int i4 = blockIdx.x*256 + threadIdx.x;    // < 16*784
  int b = i4 / 784, p = (i4 % 784) * 4;
  const float* ap = ya + (size_t)b*CHW + p;
  const float* bp = yb + (size_t)b*CHW + p;
  float4 s = {0.f,0.f,0.f,0.f};
  for (int d = 0; d < 96; ++d){
    float4 av = *(const float4*)&ap[(size_t)d*Lpx];
    float4 bv = *(const float4*)&bp[(size_t)d*Lpx];
    s.x += av.x + bv.x; s.y += av.y + bv.y; s.z += av.z + bv.z; s.w += av.w + bv.w;
  }
  float4 mu; mu.x = s.x*(1.f/96.f); mu.y = s.y*(1.f/96.f); mu.z = s.z*(1.f/96.f); mu.w = s.w*(1.f/96.f);
  float4 ss = {0.f,0.f,0.f,0.f};
  for (int d = 0; d < 96; ++d){
    float4 av = *(const float4*)&ap[(size_t)d*Lpx];
    float4 bv = *(const float4*)&bp[(size_t)d*Lpx];
    float vx = av.x + bv.x - mu.x, vy = av.y + bv.y - mu.y;
    float vz = av.z + bv.z - mu.z, vw = av.w + bv.w - mu.w;
    ss.x = fmaf(vx,vx,ss.x); ss.y = fmaf(vy,vy,ss.y); ss.z = fmaf(vz,vz,ss.z); ss.w = fmaf(vw,vw,ss.w);
  }
  float4 rs;
  rs.x = 1.f/sqrtf(ss.x*(1.f/96.f) + 1e-5f); rs.y = 1.f/sqrtf(ss.y*(1.f/96.f) + 1e-5f);
  rs.z = 1.f/sqrtf(ss.z*(1.f/96.f) + 1e-5f); rs.w = 1.f/sqrtf(ss.w*(1.f/96.f) + 1e-5f);
  float* op = out + (size_t)b*CHW + p;
  for (int d = 0; d < 96; ++d){
    float4 av = *(const float4*)&ap[(size_t)d*Lpx];
    float4 bv = *(const float4*)&bp[(size_t)d*Lpx];
    float gd = g[d], bd = be[d];
    float4 o;
    o.x = (av.x + bv.x - mu.x)*rs.x*gd + bd;
    o.y = (av.y + bv.y - mu.y)*rs.y*gd + bd;
    o.z = (av.z + bv.z - mu.z)*rs.z*gd + bd;
    o.w = (av.w + bv.w - mu.w)*rs.w*gd + bd;
    *(float4*)&op[(size_t)d*Lpx] = o;
  }
}

// ---------------- LIF over T=4 + multiply with original x (float4) ----------------
__global__ __launch_bounds__(256) void k_lif2(const float* __restrict__ yo, const float* __restrict__ x0,
                                              float* __restrict__ out){
  const int stride4 = 301056;   // B*C*L/4
  int i4 = blockIdx.x*256 + threadIdx.x;
  float4 v = {0.f,0.f,0.f,0.f};
  #pragma unroll
  for (int t = 0; t < 4; ++t){
    float4 z = *(const float4*)&yo[((size_t)t*stride4 + i4)*4];
    float4 xv = *(const float4*)&x0[((size_t)t*stride4 + i4)*4];
    v.x = 0.5f*(v.x + z.x); v.y = 0.5f*(v.y + z.y);
    v.z = 0.5f*(v.z + z.z); v.w = 0.5f*(v.w + z.w);
    float4 o;
    o.x = (v.x >= 1.0f) ? xv.x : 0.f; o.y = (v.y >= 1.0f) ? xv.y : 0.f;
    o.z = (v.z >= 1.0f) ? xv.z : 0.f; o.w = (v.w >= 1.0f) ? xv.w : 0.f;
    v.x = (v.x >= 1.0f) ? 0.f : v.x; v.y = (v.y >= 1.0f) ? 0.f : v.y;
    v.z = (v.z >= 1.0f) ? 0.f : v.z; v.w = (v.w >= 1.0f) ? 0.f : v.w;
    *(float4*)&out[((size_t)t*stride4 + i4)*4] = o;
  }
}

extern "C" void kernel_launch(void* const* d_in, const int* in_sizes, int n_in,
                              void* d_out, int out_size, void* d_ws, size_t ws_size,
                              hipStream_t stream) {
  const float* x    = (const float*)d_in[0];
  const float* ipw  = (const float*)d_in[1];
  const float* ipb  = (const float*)d_in[2];
  const float* cw   = (const float*)d_in[3];
  const float* cb   = (const float*)d_in[4];
  const float* siw  = (const float*)d_in[5];
  const float* scw  = (const float*)d_in[6];
  const float* xpw  = (const float*)d_in[7];
  const float* dtw  = (const float*)d_in[8];
  const float* dtb  = (const float*)d_in[9];
  const float* alog = (const float*)d_in[10];
  const float* dsv  = (const float*)d_in[11];
  const float* lng  = (const float*)d_in[12];
  const float* lnb  = (const float*)d_in[13];
  const float* opw  = (const float*)d_in[14];

  float* s1 = (float*)d_ws;
  float* s2 = s1 + SZn;
  float* s3 = s2 + SZn;
  float* s4 = s3 + SZn;
  float* pr  = s4 + SZn;
  float* prT = pr + PRJ;

  // 1) in_proj -> xp in s1
  k_matmul<<<784, 256, 0, stream>>>(x, ipw, ipb, s1);
  // 2) LIF over 16 steps -> uchar spikes in s2
  k_lif1<<<294, 256, 0, stream>>>(s1, (unsigned char*)s2);
  // 3) dense 3x3 conv + bias + silu -> xc in s1
  k_conv3<<<dim3(16, 6, 14), 256, 0, stream>>>((const unsigned char*)s2, cw, cb, s1);
  // 4) ssm_in matmul -> s2
  k_matmul<<<784, 256, 0, stream>>>(s1, siw, nullptr, s2);
  // 5) depthwise conv + silu -> xss rm in s1, cm in s3
  k_dwconv<<<1536, 256, 0, stream>>>(s2, scw, s1, s3);
  // 6) projections (pixel-indexed, both layouts)
  k_proj<<<896, 256, 0, stream>>>(s1, xpw, pr, prT);
  // 7) both scan dir-pairs: ya -> s2, yb(row-major) -> s4
  k_scan2<<<dim3(1536, 2), 256, 0, stream>>>(s1, s3, pr, prT, dtw, dtb, alog, dsv, s2, s4);
  // 8) combine + LayerNorm -> s3
  k_ln<<<49, 256, 0, stream>>>(s2, s4, lng, lnb, s3);
  // 9) out_proj -> s2
  k_matmul<<<784, 256, 0, stream>>>(s3, opw, nullptr, s2);
  // 10) LIF over T=4, multiply with x -> d_out
  k_lif2<<<1176, 256, 0, stream>>>(s2, x, (float*)d_out);
}